// Round 6
// baseline (293.741 us; speedup 1.0000x reference)
//
#include <hip/hip_runtime.h>
#include <stdint.h>

#define B_ROWS 8192
#define I_DIM  1024
#define N_DIM  1024
#define NDEG   9                  // D+1 (d = 0..8)
#define K_DIM  (I_DIM * (NDEG-1)) // 8192; k = i*8 + (d-1), d = 1..8 (d=0 folded into bias)

#define BM 256
#define BN 128
#define BK 64
#define NT (K_DIM / BK)           // 128 K-tiles; tile kt covers i in [kt*8, kt*8+8)

typedef __attribute__((ext_vector_type(8)))  short short8;
typedef __attribute__((ext_vector_type(16))) float f32x16;

__device__ __forceinline__ unsigned short f2bf(float f) {
  union { float f; uint32_t u; } v; v.f = f;
  uint32_t u = v.u;
  u += 0x7FFFu + ((u >> 16) & 1u);   // round-to-nearest-even
  return (unsigned short)(u >> 16);
}

__device__ __forceinline__ float bf2f(unsigned short h) {
  union { uint32_t u; float f; } v; v.u = ((uint32_t)h) << 16;
  return v.f;
}

// packed f32->bf16 (RTNE), 1 instr for 2 values; no builtin on gfx950, asm only
__device__ __forceinline__ uint32_t pk_bf16(float lo, float hi) {
  uint32_t r;
  asm("v_cvt_pk_bf16_f32 %0, %1, %2" : "=v"(r) : "v"(lo), "v"(hi));
  return r;
}

// fast tanh: 1 - 2/(e^{2x}+1); exact limits at +-inf, err ~1e-7 << bf16 quantization
__device__ __forceinline__ float fast_tanh(float x) {
  float e = __expf(2.0f * x);
  return 1.0f - __fdividef(2.0f, e + 1.0f);
}

__device__ __forceinline__ int h2(int r) { return (r >> 2) & 7; }

// ---------------- repack: C[i,o,d] fp32 -> Bt[o, i*8+(d-1)] bf16 (d>=1); bias[o] += sum_i C[i,o,0]
__global__ __launch_bounds__(256) void repack_kernel(const float* __restrict__ cf,
                                                     unsigned short* __restrict__ Bt,
                                                     float* __restrict__ bias) {
  __shared__ unsigned short L[32][584];   // [i_local][o_local*9+d], padded
  const int i0  = blockIdx.x * 32;
  const int o0  = blockIdx.y * 64;
  const int tid = threadIdx.x;

  #pragma unroll
  for (int j = 0; j < 18; ++j) {               // 18*256 = 4608 float4 = 32*576 floats
    const int f4  = j * 256 + tid;
    const int il  = f4 / 144;
    const int odq = f4 % 144;
    const float4 v = *reinterpret_cast<const float4*>(
        cf + ((size_t)(i0 + il) * N_DIM + o0) * NDEG + (size_t)odq * 4);
    ushort4 w;
    w.x = f2bf(v.x); w.y = f2bf(v.y); w.z = f2bf(v.z); w.w = f2bf(v.w);
    *reinterpret_cast<ushort4*>(&L[il][odq * 4]) = w;
  }
  __syncthreads();

  // one (o, i-octet) unit per thread: 64 consecutive shorts = 8 i x 8 d
  const int o  = tid >> 2;        // 0..63
  const int ci = tid & 3;         // 0..3
  const size_t base = (size_t)(o0 + o) * K_DIM + (size_t)(i0 + ci * 8) * 8;
  #pragma unroll
  for (int p = 0; p < 8; ++p) {   // i = i0 + ci*8 + p; shorts [d-1 = 0..7]
    const int il = ci * 8 + p;
    uint4 u;
    u.x = (uint32_t)L[il][o*9 + 1] | ((uint32_t)L[il][o*9 + 2] << 16);
    u.y = (uint32_t)L[il][o*9 + 3] | ((uint32_t)L[il][o*9 + 4] << 16);
    u.z = (uint32_t)L[il][o*9 + 5] | ((uint32_t)L[il][o*9 + 6] << 16);
    u.w = (uint32_t)L[il][o*9 + 7] | ((uint32_t)L[il][o*9 + 8] << 16);
    *reinterpret_cast<uint4*>(Bt + base + (size_t)p * 8) = u;
  }
  if (tid < 64) {
    float s = 0.f;
    #pragma unroll
    for (int il = 0; il < 32; ++il) s += bf2f(L[il][tid * 9]);
    atomicAdd(&bias[o0 + tid], s);
  }
}

// ---------------- fused basis+GEMM: C[m,n] = bias[n] + sum_k T(x)[m,k]*Bt[n,k] ------------
// A (134 MB HBM round-trip) is ELIMINATED: with k = i*8+(d-1), a 256x64 A-tile derives
// from 256x8 x-values. Each thread: 4 x-loads (coalesced f32), tanh+clamp, 7-FMA Chebyshev
// recurrence, pk_bf16 pack, one ds_write_b128 per value into the swizzled A-LDS slot the
// DMA used to fill. Fragment reads + ks-interleaved MFMA (R4's verified +8% structure)
// unchanged. Double-buffered A(2x32K)+B(2x16K) = 96 KB. Basis for kt+1 computed after the
// MFMA cluster (sched_barrier-fenced) so the x-load wait hides under ~1000 cy of MFMA.
// XCD swizzle: 8 n-blocks sharing an x-slab (1 MB) -> same XCD's L2.
__global__ __launch_bounds__(512, 2) void gemm_kernel(const float* __restrict__ x,
                                                      const unsigned short* __restrict__ Bt,
                                                      const float* __restrict__ bias,
                                                      float* __restrict__ C) {
  extern __shared__ unsigned short sm[];   // As: [2][16384] @0 ; Bs: [2][8192] @32768
  const int tid  = threadIdx.x;
  const int lane = tid & 63;
  const int wave = tid >> 6;        // 0..7
  const int l31  = lane & 31;
  const int half = lane >> 5;       // 0..1 -> k-offset 8*half
  const int wm   = wave >> 1;       // 0..3
  const int wn   = wave & 1;        // 0..1

  // bijective XCD swizzle (grid = 256 = 32 m-tiles x 8 n-tiles, round-robin %8 -> XCD):
  // blocks with the same m-tile get the same bid%8 -> same XCD -> x-slab L2 reuse.
  const int bid = blockIdx.x;
  const int mt  = (bid & 7) + 8 * (bid >> 6);
  const int nt  = (bid >> 3) & 7;
  const int m0  = mt * BM;
  const int n0  = nt * BN;

  const int sr   = tid >> 3;        // 0..63: staging row / basis row-quarter
  const int slot = tid & 7;         // 16B chunk slot (staging) / basis i_loc

  const unsigned short* Bbase = Bt + (size_t)n0 * K_DIM;

  f32x16 acc[2][2];
  #pragma unroll
  for (int a = 0; a < 2; ++a)
    #pragma unroll
    for (int b = 0; b < 2; ++b)
      #pragma unroll
      for (int r = 0; r < 16; ++r)
        acc[a][b][r] = 0.f;

#define STAGE_B(s, bf, kk) { const int r_ = (s)*64 + sr; const int gc_ = slot ^ h2(r_);     \
    __builtin_amdgcn_global_load_lds(                                                       \
        (const __attribute__((address_space(1))) void*)(Bbase + (size_t)r_*K_DIM + (kk) + gc_*8), \
        (__attribute__((address_space(3))) void*)&sm[32768 + (bf)*8192 + r_*64 + slot*8], 16, 0, 0); }

// x prefetch for tile tt: thread (sr, slot) covers rows sr+64q, i = tt*8+slot (coalesced:
// 8 rows x 32B contiguous per wave)
#define LOADX(xr, tt) {                                                                     \
    _Pragma("unroll")                                                                       \
    for (int q = 0; q < 4; ++q)                                                             \
      xr[q] = x[(size_t)(m0 + q*64 + sr) * I_DIM + (tt)*8 + slot]; }

// basis: T_1..T_8(clamp(tanh(xr[q]))) -> 16B at As[buf][row][chunk slot^h2(row)]
#define BASIS(bf, xr) {                                                                     \
    _Pragma("unroll")                                                                       \
    for (int q = 0; q < 4; ++q) {                                                           \
      const int r_ = q*64 + sr;                                                             \
      float t = fast_tanh(xr[q]);                                                           \
      t = fminf(fmaxf(t, -0.999f), 0.999f);                                                 \
      const float t2 = t + t;                                                               \
      const float T1 = t;                                                                   \
      const float T2 = t2*t - 1.0f;                                                         \
      const float T3 = t2*T2 - T1;                                                          \
      const float T4 = t2*T3 - T2;                                                          \
      const float T5 = t2*T4 - T3;                                                          \
      const float T6 = t2*T5 - T4;                                                          \
      const float T7 = t2*T6 - T5;                                                          \
      const float T8 = t2*T7 - T6;                                                          \
      uint4 u;                                                                              \
      u.x = pk_bf16(T1, T2); u.y = pk_bf16(T3, T4);                                         \
      u.z = pk_bf16(T5, T6); u.w = pk_bf16(T7, T8);                                         \
      *reinterpret_cast<uint4*>(&sm[(bf)*16384 + r_*64 + ((slot ^ h2(r_)))*8]) = u;         \
    } }

  // prologue: stage B-tile 0, load+compute basis-tile 0
  { STAGE_B(0, 0, 0) STAGE_B(1, 0, 0) }
  float xr[4];
  LOADX(xr, 0)
  BASIS(0, xr)
  __syncthreads();

  const int rowA0 = wm * 64 + l31;
  const int rowA1 = wm * 64 + 32 + l31;
  const int rowB0 = wn * 64 + l31;
  const int rowB1 = wn * 64 + 32 + l31;
  const int hA0 = h2(rowA0), hA1 = h2(rowA1), hB0 = h2(rowB0), hB1 = h2(rowB1);

  for (int kt = 0; kt < NT; ++kt) {
    const int  cur  = kt & 1;
    const int  nxt  = cur ^ 1;
    const bool more = (kt + 1 < NT);
    const unsigned short* Asc = &sm[cur * 16384];
    const unsigned short* Bsc = &sm[32768 + cur * 8192];

    // issue next tile's B-stage + x-prefetch at tile top (full tile of latency)
    if (more) { STAGE_B(0, nxt, (kt + 1) * BK) STAGE_B(1, nxt, (kt + 1) * BK) LOADX(xr, kt + 1) }
    __builtin_amdgcn_sched_barrier(0);

    short8 av[2][4], bv[2][4];
#define READ4(ks) {                                                                          \
    const int c_ = (ks) * 2 + half;                                                          \
    av[0][ks] = *reinterpret_cast<const short8*>(&Asc[rowA0 * 64 + (c_ ^ hA0) * 8]);         \
    av[1][ks] = *reinterpret_cast<const short8*>(&Asc[rowA1 * 64 + (c_ ^ hA1) * 8]);         \
    bv[0][ks] = *reinterpret_cast<const short8*>(&Bsc[rowB0 * 64 + (c_ ^ hB0) * 8]);         \
    bv[1][ks] = *reinterpret_cast<const short8*>(&Bsc[rowB1 * 64 + (c_ ^ hB1) * 8]); }

    READ4(0)
    #pragma unroll
    for (int ks = 0; ks < 4; ++ks) {
      if (ks < 3) READ4(ks + 1)
      acc[0][0] = __builtin_amdgcn_mfma_f32_32x32x16_bf16(av[0][ks], bv[0][ks], acc[0][0], 0, 0, 0);
      acc[0][1] = __builtin_amdgcn_mfma_f32_32x32x16_bf16(av[0][ks], bv[1][ks], acc[0][1], 0, 0, 0);
      acc[1][0] = __builtin_amdgcn_mfma_f32_32x32x16_bf16(av[1][ks], bv[0][ks], acc[1][0], 0, 0, 0);
      acc[1][1] = __builtin_amdgcn_mfma_f32_32x32x16_bf16(av[1][ks], bv[1][ks], acc[1][1], 0, 0, 0);
      // pin the interleave: [4 ds_read][4 mfma] per ks step (R4's verified +8%)
      if (ks < 3) __builtin_amdgcn_sched_group_barrier(0x100, 4, 0);  // DS_READ
      __builtin_amdgcn_sched_group_barrier(0x008, 4, 0);              // MFMA
    }
#undef READ4

    // basis for kt+1 AFTER the MFMA cluster: the xr vmcnt-wait lands here, hidden
    // under ~1000 cy of MFMA issued above; ds_writes go to the nxt buffer.
    __builtin_amdgcn_sched_barrier(0);
    if (more) BASIS(nxt, xr)

    // tile boundary: drains B-stage DMA (vmcnt) + basis ds_writes (lgkm) + barrier
    __syncthreads();
  }
#undef STAGE_B
#undef LOADX
#undef BASIS

  // epilogue: 32x32 C/D layout col = lane&31, row = (reg&3) + 8*(reg>>2) + 4*(lane>>5)
  #pragma unroll
  for (int ni = 0; ni < 2; ++ni) {
    const int col  = n0 + wn * 64 + ni * 32 + l31;
    const float bc = bias[col];
    #pragma unroll
    for (int mi = 0; mi < 2; ++mi) {
      const int rbase = m0 + wm * 64 + mi * 32 + 4 * half;
      #pragma unroll
      for (int r = 0; r < 16; ++r) {
        const int row = rbase + (r & 3) + 8 * (r >> 2);
        C[(size_t)row * N_DIM + col] = acc[mi][ni][r] + bc;
      }
    }
  }
}

extern "C" void kernel_launch(void* const* d_in, const int* in_sizes, int n_in,
                              void* d_out, int out_size, void* d_ws, size_t ws_size,
                              hipStream_t stream) {
  const float* x      = (const float*)d_in[0];
  const float* coeffs = (const float*)d_in[1];
  float* y            = (float*)d_out;

  const size_t bt_bytes = (size_t)N_DIM * K_DIM * sizeof(unsigned short); // 16.78 MB
  unsigned short* Bt = (unsigned short*)d_ws;
  float* bias        = (float*)((char*)d_ws + bt_bytes);

  // bias accumulator must start at zero (ws is poisoned 0xAA each call)
  hipMemsetAsync(bias, 0, N_DIM * sizeof(float), stream);

  // 96 KB dynamic LDS for the gemm (double-buffered A+B)
  hipFuncSetAttribute((const void*)gemm_kernel,
                      hipFuncAttributeMaxDynamicSharedMemorySize, 98304);

  repack_kernel<<<dim3(I_DIM / 32, N_DIM / 64), 256, 0, stream>>>(coeffs, Bt, bias);
  gemm_kernel<<<(B_ROWS / BM) * (N_DIM / BN), 512, 98304, stream>>>(x, Bt, bias, y);
}

// Round 7
// 255.978 us; speedup vs baseline: 1.1475x; 1.1475x over previous
//
#include <hip/hip_runtime.h>
#include <stdint.h>

#define B_ROWS 8192
#define I_DIM  1024
#define N_DIM  1024
#define NDEG   9                  // D+1 (d = 0..8)
#define K_DIM  (I_DIM * (NDEG-1)) // 8192; k = i*8 + (d-1), d = 1..8 (d=0 folded into bias)

#define BM 256
#define BN 128
#define BK 64
#define NT (K_DIM / BK)           // 128 K-tiles; tile kt covers i in [kt*8, kt*8+8)

typedef __attribute__((ext_vector_type(8)))  short short8;
typedef __attribute__((ext_vector_type(16))) float f32x16;

__device__ __forceinline__ unsigned short f2bf(float f) {
  union { float f; uint32_t u; } v; v.f = f;
  uint32_t u = v.u;
  u += 0x7FFFu + ((u >> 16) & 1u);   // round-to-nearest-even
  return (unsigned short)(u >> 16);
}

__device__ __forceinline__ float bf2f(unsigned short h) {
  union { uint32_t u; float f; } v; v.u = ((uint32_t)h) << 16;
  return v.f;
}

// packed f32->bf16 (RTNE), 1 instr for 2 values; no builtin on gfx950, asm only
__device__ __forceinline__ uint32_t pk_bf16(float lo, float hi) {
  uint32_t r;
  asm("v_cvt_pk_bf16_f32 %0, %1, %2" : "=v"(r) : "v"(lo), "v"(hi));
  return r;
}

// fast tanh: 1 - 2/(e^{2x}+1); exact limits at +-inf, err ~1e-7 << bf16 quantization
__device__ __forceinline__ float fast_tanh(float x) {
  float e = __expf(2.0f * x);
  return 1.0f - __fdividef(2.0f, e + 1.0f);
}

__device__ __forceinline__ int h2(int r) { return (r >> 2) & 7; }

// ---------------- repack: C[i,o,d] fp32 -> Bt[o, i*8+(d-1)] bf16 (d>=1); bias[o] += sum_i C[i,o,0]
__global__ __launch_bounds__(256) void repack_kernel(const float* __restrict__ cf,
                                                     unsigned short* __restrict__ Bt,
                                                     float* __restrict__ bias) {
  __shared__ unsigned short L[32][584];   // [i_local][o_local*9+d], padded
  const int i0  = blockIdx.x * 32;
  const int o0  = blockIdx.y * 64;
  const int tid = threadIdx.x;

  #pragma unroll
  for (int j = 0; j < 18; ++j) {               // 18*256 = 4608 float4 = 32*576 floats
    const int f4  = j * 256 + tid;
    const int il  = f4 / 144;
    const int odq = f4 % 144;
    const float4 v = *reinterpret_cast<const float4*>(
        cf + ((size_t)(i0 + il) * N_DIM + o0) * NDEG + (size_t)odq * 4);
    ushort4 w;
    w.x = f2bf(v.x); w.y = f2bf(v.y); w.z = f2bf(v.z); w.w = f2bf(v.w);
    *reinterpret_cast<ushort4*>(&L[il][odq * 4]) = w;
  }
  __syncthreads();

  // one (o, i-octet) unit per thread: 64 consecutive shorts = 8 i x 8 d
  const int o  = tid >> 2;        // 0..63
  const int ci = tid & 3;         // 0..3
  const size_t base = (size_t)(o0 + o) * K_DIM + (size_t)(i0 + ci * 8) * 8;
  #pragma unroll
  for (int p = 0; p < 8; ++p) {   // i = i0 + ci*8 + p; shorts [d-1 = 0..7]
    const int il = ci * 8 + p;
    uint4 u;
    u.x = (uint32_t)L[il][o*9 + 1] | ((uint32_t)L[il][o*9 + 2] << 16);
    u.y = (uint32_t)L[il][o*9 + 3] | ((uint32_t)L[il][o*9 + 4] << 16);
    u.z = (uint32_t)L[il][o*9 + 5] | ((uint32_t)L[il][o*9 + 6] << 16);
    u.w = (uint32_t)L[il][o*9 + 7] | ((uint32_t)L[il][o*9 + 8] << 16);
    *reinterpret_cast<uint4*>(Bt + base + (size_t)p * 8) = u;
  }
  if (tid < 64) {
    float s = 0.f;
    #pragma unroll
    for (int il = 0; il < 32; ++il) s += bf2f(L[il][tid * 9]);
    atomicAdd(&bias[o0 + tid], s);
  }
}

// ---------------- fused basis+GEMM: C[m,n] = bias[n] + sum_k T(x)[m,k]*Bt[n,k] ------------
// R6 fused the basis but appended it serially after the MFMA cluster (sched-fenced) ->
// +1550 cy/tile. This version INTERLEAVES one basis-quarter per ks step, pinned
// [DS_READ 4][DS_WRITE 1][MFMA 4], so basis VALU hides under the MFMA pipe. x is
// prefetched TWO tiles ahead (xrA/xrB ping-pong, kt unrolled x2); barriers are counted
// (vmcnt(4) keeps x-loads in flight) instead of __syncthreads' vmcnt(0) drain; basis
// write offsets and x pointers are hoisted out of the loop.
__global__ __launch_bounds__(512, 2) void gemm_kernel(const float* __restrict__ x,
                                                      const unsigned short* __restrict__ Bt,
                                                      const float* __restrict__ bias,
                                                      float* __restrict__ C) {
  extern __shared__ unsigned short sm[];   // As: [2][16384] @0 ; Bs: [2][8192] @32768
  const int tid  = threadIdx.x;
  const int lane = tid & 63;
  const int wave = tid >> 6;        // 0..7
  const int l31  = lane & 31;
  const int half = lane >> 5;       // 0..1 -> k-offset 8*half
  const int wm   = wave >> 1;       // 0..3
  const int wn   = wave & 1;        // 0..1

  // bijective XCD swizzle: all 8 n-blocks of one m-tile share bid%8 -> same XCD L2
  const int bid = blockIdx.x;
  const int mt  = (bid & 7) + 8 * (bid >> 6);
  const int nt  = (bid >> 3) & 7;
  const int m0  = mt * BM;
  const int n0  = nt * BN;

  const int sr   = tid >> 3;        // 0..63: staging row / basis row-quarter
  const int slot = tid & 7;         // 16B chunk slot (staging) / basis i_loc

  const unsigned short* Bbase = Bt + (size_t)n0 * K_DIM;

  // hoisted basis constants: LDS write offsets (shorts, within an A-buffer) + x pointers
  int awoff[4];
  const float* xptr[4];
  #pragma unroll
  for (int q = 0; q < 4; ++q) {
    const int r_ = q * 64 + sr;
    awoff[q] = r_ * 64 + (slot ^ h2(r_)) * 8;
    xptr[q]  = x + (size_t)(m0 + r_) * I_DIM + slot;
  }

  f32x16 acc[2][2];
  #pragma unroll
  for (int a = 0; a < 2; ++a)
    #pragma unroll
    for (int b = 0; b < 2; ++b)
      #pragma unroll
      for (int r = 0; r < 16; ++r)
        acc[a][b][r] = 0.f;

#define STAGE_B(s, bf, kk) { const int r_ = (s)*64 + sr; const int gc_ = slot ^ h2(r_);     \
    __builtin_amdgcn_global_load_lds(                                                       \
        (const __attribute__((address_space(1))) void*)(Bbase + (size_t)r_*K_DIM + (kk) + gc_*8), \
        (__attribute__((address_space(3))) void*)&sm[32768 + (bf)*8192 + r_*64 + slot*8], 16, 0, 0); }

#define LOADX(xr, tt) {                                                                     \
    _Pragma("unroll")                                                                       \
    for (int q = 0; q < 4; ++q) xr[q] = xptr[q][(tt) * 8]; }

// one basis quarter: row q*64+sr, value = T_1..T_8(clamp(tanh(xv))) -> 16B LDS write
#define BASIS_Q(bf, q, xv) {                                                                \
      float t = fast_tanh(xv);                                                              \
      t = fminf(fmaxf(t, -0.999f), 0.999f);                                                 \
      const float t2 = t + t;                                                               \
      const float T1 = t;                                                                   \
      const float T2 = t2*t - 1.0f;                                                         \
      const float T3 = t2*T2 - T1;                                                          \
      const float T4 = t2*T3 - T2;                                                          \
      const float T5 = t2*T4 - T3;                                                          \
      const float T6 = t2*T5 - T4;                                                          \
      const float T7 = t2*T6 - T5;                                                          \
      const float T8 = t2*T7 - T6;                                                          \
      uint4 u;                                                                              \
      u.x = pk_bf16(T1, T2); u.y = pk_bf16(T3, T4);                                         \
      u.z = pk_bf16(T5, T6); u.w = pk_bf16(T7, T8);                                         \
      *reinterpret_cast<uint4*>(&sm[(bf)*16384 + awoff[q]]) = u; }

  const int rowA0 = wm * 64 + l31;
  const int rowA1 = wm * 64 + 32 + l31;
  const int rowB0 = wn * 64 + l31;
  const int rowB1 = wn * 64 + 32 + l31;
  const int hA0 = h2(rowA0), hA1 = h2(rowA1), hB0 = h2(rowB0), hB1 = h2(rowB1);

#define READ4(Asc, Bsc, av, bv, ks) {                                                        \
    const int c_ = (ks) * 2 + half;                                                          \
    av[0][ks] = *reinterpret_cast<const short8*>(&Asc[rowA0 * 64 + (c_ ^ hA0) * 8]);         \
    av[1][ks] = *reinterpret_cast<const short8*>(&Asc[rowA1 * 64 + (c_ ^ hA1) * 8]);         \
    bv[0][ks] = *reinterpret_cast<const short8*>(&Bsc[rowB0 * 64 + (c_ ^ hB0) * 8]);         \
    bv[1][ks] = *reinterpret_cast<const short8*>(&Bsc[rowB1 * 64 + (c_ ^ hB1) * 8]); }

#define MFMA4(av, bv, ks)                                                                    \
    acc[0][0] = __builtin_amdgcn_mfma_f32_32x32x16_bf16(av[0][ks], bv[0][ks], acc[0][0], 0, 0, 0); \
    acc[0][1] = __builtin_amdgcn_mfma_f32_32x32x16_bf16(av[0][ks], bv[1][ks], acc[0][1], 0, 0, 0); \
    acc[1][0] = __builtin_amdgcn_mfma_f32_32x32x16_bf16(av[1][ks], bv[0][ks], acc[1][0], 0, 0, 0); \
    acc[1][1] = __builtin_amdgcn_mfma_f32_32x32x16_bf16(av[1][ks], bv[1][ks], acc[1][1], 0, 0, 0);

// full tile: stage B for kt+1, optionally prefetch x for kt+2, interleaved
// [reads | basis-quarter(kt+1) | MFMA] per ks, counted-vmcnt barrier.
#define TILE_FULL(kt_, XC, XL, LOADEN) {                                                     \
    const int cur_ = (kt_) & 1; const int nxt_ = cur_ ^ 1;                                   \
    const unsigned short* Asc = &sm[cur_ * 16384];                                           \
    const unsigned short* Bsc = &sm[32768 + cur_ * 8192];                                    \
    STAGE_B(0, nxt_, ((kt_) + 1) * BK) STAGE_B(1, nxt_, ((kt_) + 1) * BK)                    \
    if (LOADEN) { LOADX(XL, (kt_) + 2) }                                                     \
    __builtin_amdgcn_sched_barrier(0);                                                       \
    short8 av[2][4], bv[2][4];                                                               \
    READ4(Asc, Bsc, av, bv, 0)                                                               \
    READ4(Asc, Bsc, av, bv, 1)                                                               \
    BASIS_Q(nxt_, 0, XC[0])                                                                  \
    MFMA4(av, bv, 0)                                                                         \
    __builtin_amdgcn_sched_group_barrier(0x100, 8, 0);                                       \
    __builtin_amdgcn_sched_group_barrier(0x200, 1, 0);                                       \
    __builtin_amdgcn_sched_group_barrier(0x008, 4, 0);                                       \
    READ4(Asc, Bsc, av, bv, 2)                                                               \
    BASIS_Q(nxt_, 1, XC[1])                                                                  \
    MFMA4(av, bv, 1)                                                                         \
    __builtin_amdgcn_sched_group_barrier(0x100, 4, 0);                                       \
    __builtin_amdgcn_sched_group_barrier(0x200, 1, 0);                                       \
    __builtin_amdgcn_sched_group_barrier(0x008, 4, 0);                                       \
    READ4(Asc, Bsc, av, bv, 3)                                                               \
    BASIS_Q(nxt_, 2, XC[2])                                                                  \
    MFMA4(av, bv, 2)                                                                         \
    __builtin_amdgcn_sched_group_barrier(0x100, 4, 0);                                       \
    __builtin_amdgcn_sched_group_barrier(0x200, 1, 0);                                       \
    __builtin_amdgcn_sched_group_barrier(0x008, 4, 0);                                       \
    BASIS_Q(nxt_, 3, XC[3])                                                                  \
    MFMA4(av, bv, 3)                                                                         \
    __builtin_amdgcn_sched_group_barrier(0x200, 1, 0);                                       \
    __builtin_amdgcn_sched_group_barrier(0x008, 4, 0);                                       \
    __builtin_amdgcn_sched_barrier(0);                                                       \
    if (LOADEN) asm volatile("s_waitcnt vmcnt(4) lgkmcnt(0)" ::: "memory");                  \
    else        asm volatile("s_waitcnt vmcnt(0) lgkmcnt(0)" ::: "memory");                  \
    __builtin_amdgcn_s_barrier();                                                            \
    __builtin_amdgcn_sched_barrier(0); }

  // prologue: stage B tile0, x for tiles 0 and 1; basis tile0 -> buf0
  float xrA[4], xrB[4];
  STAGE_B(0, 0, 0) STAGE_B(1, 0, 0)
  LOADX(xrA, 0)
  LOADX(xrB, 1)
  asm volatile("s_waitcnt vmcnt(4)" ::: "memory");   // B stages + xrA done; xrB in flight
  BASIS_Q(0, 0, xrA[0]) BASIS_Q(0, 1, xrA[1]) BASIS_Q(0, 2, xrA[2]) BASIS_Q(0, 3, xrA[3])
  asm volatile("s_waitcnt lgkmcnt(0)" ::: "memory");
  __builtin_amdgcn_s_barrier();
  __builtin_amdgcn_sched_barrier(0);

  // main loop: tiles 0..125 (basis+load), tile 126 (basis, no load), tile 127 (compute only)
  for (int kt = 0; kt < 126; kt += 2) {
    TILE_FULL(kt,     xrB, xrA, 1)     // even: consume xrB (x of kt+1), load xrA (x of kt+2)
    TILE_FULL(kt + 1, xrA, xrB, 1)     // odd : consume xrA,            load xrB
  }
  TILE_FULL(126, xrB, xrA, 0)          // basis for t127 from xrB; nothing left to load

  { // tile 127: compute only
    const unsigned short* Asc = &sm[1 * 16384];
    const unsigned short* Bsc = &sm[32768 + 1 * 8192];
    short8 av[2][4], bv[2][4];
    READ4(Asc, Bsc, av, bv, 0)
    #pragma unroll
    for (int ks = 0; ks < 4; ++ks) {
      if (ks < 3) READ4(Asc, Bsc, av, bv, ks + 1)
      MFMA4(av, bv, ks)
      if (ks < 3) __builtin_amdgcn_sched_group_barrier(0x100, 4, 0);
      __builtin_amdgcn_sched_group_barrier(0x008, 4, 0);
    }
  }
#undef TILE_FULL
#undef MFMA4
#undef READ4
#undef BASIS_Q
#undef LOADX
#undef STAGE_B

  // epilogue: 32x32 C/D layout col = lane&31, row = (reg&3) + 8*(reg>>2) + 4*(lane>>5)
  #pragma unroll
  for (int ni = 0; ni < 2; ++ni) {
    const int col  = n0 + wn * 64 + ni * 32 + l31;
    const float bc = bias[col];
    #pragma unroll
    for (int mi = 0; mi < 2; ++mi) {
      const int rbase = m0 + wm * 64 + mi * 32 + 4 * half;
      #pragma unroll
      for (int r = 0; r < 16; ++r) {
        const int row = rbase + (r & 3) + 8 * (r >> 2);
        C[(size_t)row * N_DIM + col] = acc[mi][ni][r] + bc;
      }
    }
  }
}

extern "C" void kernel_launch(void* const* d_in, const int* in_sizes, int n_in,
                              void* d_out, int out_size, void* d_ws, size_t ws_size,
                              hipStream_t stream) {
  const float* x      = (const float*)d_in[0];
  const float* coeffs = (const float*)d_in[1];
  float* y            = (float*)d_out;

  const size_t bt_bytes = (size_t)N_DIM * K_DIM * sizeof(unsigned short); // 16.78 MB
  unsigned short* Bt = (unsigned short*)d_ws;
  float* bias        = (float*)((char*)d_ws + bt_bytes);

  // bias accumulator must start at zero (ws is poisoned 0xAA each call)
  hipMemsetAsync(bias, 0, N_DIM * sizeof(float), stream);

  // 96 KB dynamic LDS for the gemm (double-buffered A+B)
  hipFuncSetAttribute((const void*)gemm_kernel,
                      hipFuncAttributeMaxDynamicSharedMemorySize, 98304);

  repack_kernel<<<dim3(I_DIM / 32, N_DIM / 64), 256, 0, stream>>>(coeffs, Bt, bias);
  gemm_kernel<<<(B_ROWS / BM) * (N_DIM / BN), 512, 98304, stream>>>(x, Bt, bias, y);
}